// Round 15
// baseline (392.792 us; speedup 1.0000x reference)
//
#include <hip/hip_runtime.h>
#include <math.h>

#define Dk 1024
#define Ck 32
#define Nk 1024
#define Qk 1024
#define REGP 0.5f
#define NB 64
#define NROWSV (Qk + Nk + Ck + 1)   // 2081 rows: queries, sorted support, mus, m

// consts layout (floats)
#define CO_KAPPA 0
#define CO_NU    1
#define CO_NJ    2
#define CO_KN    34
#define CO_SCALE 66
#define CO_COMMON 98
#define CO_COEF  130
#define CO_BIASA 162
#define CO_BIASF 200

// workspace offsets (floats). Offset 0 = Yo32 (fp32 accum), later aliased by P.
#define O_P    0u
#define O_W    2162688u
#define O_T    3211264u
#define O_MU   3473408u
#define O_QM   3506176u
#define O_MB   3538944u
#define O_MI   3578112u
#define O_QNY  3617280u
#define O_QNO  3618304u
#define O_MUN  3619328u
#define O_GMM  3619360u
#define O_EX   3619392u
#define O_CONS 3619408u
#define O_CIDX 3619664u
// bf16 split matrices (ushort storage, offsets in floats)
#define O_YH   3652432u
#define O_YM   4733776u
#define O_YL   5815120u
#define O_WH   6896464u
#define O_WM   7420752u
#define O_WL   7945040u
#define O_OH   8469328u
#define O_OM   9550672u
#define O_OL   10632016u
// total = 11,713,360 floats = 46.9 MB

#define WS_DECL \
    float* P     = Wbuf + O_P;    (void)P; \
    float* W     = Wbuf + O_W;    (void)W; \
    float* Tb    = Wbuf + O_T;    (void)Tb; \
    float* QM    = Wbuf + O_QM;   (void)QM; \
    float* Mbuf  = Wbuf + O_MB;   (void)Mbuf; \
    float* Minv  = Wbuf + O_MI;   (void)Minv; \
    float* qny   = Wbuf + O_QNY;  (void)qny; \
    float* qno   = Wbuf + O_QNO;  (void)qno; \
    float* mun2o = Wbuf + O_MUN;  (void)mun2o; \
    float* gmm   = Wbuf + O_GMM;  (void)gmm; \
    float* extraf= Wbuf + O_EX;   (void)extraf; \
    float* cons  = Wbuf + O_CONS; (void)cons; \
    int*   cidx  = (int*)(Wbuf + O_CIDX); (void)cidx; \
    ushort* sYh = (ushort*)(Wbuf + O_YH); (void)sYh; \
    ushort* sYm = (ushort*)(Wbuf + O_YM); (void)sYm; \
    ushort* sYl = (ushort*)(Wbuf + O_YL); (void)sYl; \
    ushort* sWh = (ushort*)(Wbuf + O_WH); (void)sWh; \
    ushort* sWm = (ushort*)(Wbuf + O_WM); (void)sWm; \
    ushort* sWl = (ushort*)(Wbuf + O_WL); (void)sWl; \
    ushort* sOh = (ushort*)(Wbuf + O_OH); (void)sOh; \
    ushort* sOm = (ushort*)(Wbuf + O_OM); (void)sOm; \
    ushort* sOl = (ushort*)(Wbuf + O_OL); (void)sOl;

typedef __attribute__((ext_vector_type(8))) __bf16 bf16x8;
typedef __attribute__((ext_vector_type(4))) float f32x4;

#define MFMA(a, b, c) __builtin_amdgcn_mfma_f32_16x16x32_bf16(a, b, c, 0, 0, 0)

__device__ __forceinline__ ushort f2bf(float x) {
    unsigned u = __float_as_uint(x);
    return (ushort)((u + 0x7FFFu + ((u >> 16) & 1u)) >> 16);
}
__device__ __forceinline__ float bf2f(ushort h) {
    return __uint_as_float(((unsigned)h) << 16);
}
__device__ __forceinline__ void split1(float x, ushort& h, ushort& m, ushort& l) {
    h = f2bf(x);
    float r1 = x - bf2f(h);
    m = f2bf(r1);
    l = f2bf(r1 - bf2f(m));
}
__device__ __forceinline__ void split_store4(ushort* ph, ushort* pm, ushort* pl,
                                             size_t o, float4 v) {
    float vv[4] = {v.x, v.y, v.z, v.w};
    ushort4 H, M, L;
    ushort* Hp = (ushort*)&H; ushort* Mp = (ushort*)&M; ushort* Lp = (ushort*)&L;
#pragma unroll
    for (int c = 0; c < 4; ++c) split1(vv[c], Hp[c], Mp[c], Lp[c]);
    *(ushort4*)(ph + o) = H;
    *(ushort4*)(pm + o) = M;
    *(ushort4*)(pl + o) = L;
}

__device__ __forceinline__ float wave_red(float s) {
#pragma unroll
    for (int o = 32; o > 0; o >>= 1) s += __shfl_down(s, o, 64);
    return s;
}

// ---------- bf16x3 MFMA tiles v5: B-only LDS, A direct-global, 64x128 block, 2x2 waves of 32x64 ----------
// LDS halfword offsets: B comps [3][128][40] (80B row stride, 2-way bank max).
#define LDSB3(c, r, k8) ((c) * 5120 + (r) * 40 + (k8))
#define LDS_HW3 15360   // 30720 B

__device__ __forceinline__ void b_fetch3(bf16x8* rb,
                                         const ushort* Bh, const ushort* Bm, const ushort* Bl,
                                         int bRow0, int kcol, int t) {
#pragma unroll
    for (int u = 0; u < 6; ++u) {
        int comp = u >> 1;
        int idx = ((u & 1) << 8) + t;     // 0..511 : row=idx>>2, kg=idx&3
        int row = idx >> 2, kg = idx & 3;
        const ushort* Bs = (comp == 0) ? Bh : ((comp == 1) ? Bm : Bl);
        rb[u] = *(const bf16x8*)(Bs + (size_t)(bRow0 + row) * 1024 + kcol + kg * 8);
    }
}
__device__ __forceinline__ void b_store3(ushort* lds, const bf16x8* rb, int t) {
#pragma unroll
    for (int u = 0; u < 6; ++u) {
        int comp = u >> 1;
        int idx = ((u & 1) << 8) + t;
        int row = idx >> 2, kg = idx & 3;
        *(bf16x8*)(lds + LDSB3(comp, row, kg * 8)) = rb[u];
    }
}
__device__ __forceinline__ void a_fetch64(bf16x8 af[2][3],
                                          const ushort* Ah, const ushort* Am, const ushort* Al,
                                          int arowT, int aRowMax, int kcol, int lk) {
    bf16x8 z = {};
#pragma unroll
    for (int rf = 0; rf < 2; ++rf) {
        int gr = arowT + rf * 16;
        bool ok = gr < aRowMax;
#pragma unroll
        for (int c = 0; c < 3; ++c) {
            const ushort* As = (c == 0) ? Ah : ((c == 1) ? Am : Al);
            af[rf][c] = ok ? *(const bf16x8*)(As + (size_t)gr * 1024 + kcol + lk * 8) : z;
        }
    }
}

// wave w (2x2): rows (w>>1)*32 (2 frags) x cols (w&1)*64 (4 frags); 6-term bf16x3.
__device__ __forceinline__ void tile_compute64(const ushort* lds, f32x4 acc[2][4],
                                               bf16x8 af[2][3], int bcol0, int lr, int lk) {
#pragma unroll
    for (int cf = 0; cf < 4; ++cf) {
        int brow = bcol0 + cf * 16 + lr;
        bf16x8 bh = *(const bf16x8*)(lds + LDSB3(0, brow, lk * 8));
        bf16x8 bm = *(const bf16x8*)(lds + LDSB3(1, brow, lk * 8));
        bf16x8 bl = *(const bf16x8*)(lds + LDSB3(2, brow, lk * 8));
#pragma unroll
        for (int rf = 0; rf < 2; ++rf) {
            f32x4 a = acc[rf][cf];
            a = MFMA(af[rf][0], bh, a);
            a = MFMA(af[rf][0], bm, a);
            a = MFMA(af[rf][1], bh, a);
            a = MFMA(af[rf][0], bl, a);
            a = MFMA(af[rf][2], bh, a);
            a = MFMA(af[rf][1], bm, a);
            acc[rf][cf] = a;
        }
    }
}

__device__ __forceinline__ void tile_gemm64(
    ushort* lds, f32x4 acc[2][4],
    const ushort* Ah, const ushort* Am, const ushort* Al, int aRow0, int aRowMax,
    const ushort* Bh, const ushort* Bm, const ushort* Bl, int bRow0,
    int kbase, int ksteps, int t)
{
    const int w = t >> 6, lr = t & 15, lk = (t >> 4) & 3;
    const int arowT = aRow0 + (w >> 1) * 32 + lr;
    const int bcol0 = (w & 1) * 64;
    bf16x8 rb[6], afc[2][3], afn[2][3];
    b_fetch3(rb, Bh, Bm, Bl, bRow0, kbase * 32, t);
    a_fetch64(afc, Ah, Am, Al, arowT, aRowMax, kbase * 32, lk);
    b_store3(lds, rb, t);
    __syncthreads();
    for (int kt = 0; kt < ksteps; ++kt) {
        if (kt + 1 < ksteps) {
            b_fetch3(rb, Bh, Bm, Bl, bRow0, (kbase + kt + 1) * 32, t);
            a_fetch64(afn, Ah, Am, Al, arowT, aRowMax, (kbase + kt + 1) * 32, lk);
        }
        tile_compute64(lds, acc, afc, bcol0, lr, lk);
        __syncthreads();
        if (kt + 1 < ksteps) {
            b_store3(lds, rb, t);
#pragma unroll
            for (int rf = 0; rf < 2; ++rf)
#pragma unroll
                for (int c = 0; c < 3; ++c) afc[rf][c] = afn[rf][c];
        }
        __syncthreads();
    }
}

// ---------- fp32 tile-GEMM machinery (trtri chain) ----------
__device__ __forceinline__ void fetch4(float4* reg, const float* src, int ld,
                                       int rowbase, int rowmax, int colbase, int t) {
#pragma unroll
    for (int u = 0; u < 4; ++u) {
        int slot = t + u * 256;
        int r = slot >> 4, c4 = slot & 15;
        int gr = rowbase + r;
        reg[u] = (gr < rowmax) ? *(const float4*)(src + (size_t)gr * ld + colbase + c4 * 4)
                               : make_float4(0.f, 0.f, 0.f, 0.f);
    }
}
__device__ __forceinline__ void stT(float* dst, const float4* reg, int t) {
#pragma unroll
    for (int u = 0; u < 4; ++u) {
        int slot = t + u * 256;
        int r = slot >> 4, c4 = slot & 15;
        dst[(c4 * 4 + 0) * 68 + r] = reg[u].x;
        dst[(c4 * 4 + 1) * 68 + r] = reg[u].y;
        dst[(c4 * 4 + 2) * 68 + r] = reg[u].z;
        dst[(c4 * 4 + 3) * 68 + r] = reg[u].w;
    }
}
__device__ __forceinline__ void stN(float* dst, const float4* reg, int t) {
#pragma unroll
    for (int u = 0; u < 4; ++u) {
        int slot = t + u * 256;
        int r = slot >> 4, c4 = slot & 15;
        *(float4*)(dst + r * 68 + c4 * 4) = reg[u];
    }
}
__device__ __forceinline__ void gemm16(const float* At, const float* Bt,
                                       float acc[4][4], int tx, int ty) {
#pragma unroll 4
    for (int kk = 0; kk < NB; ++kk) {
        float4 a = *(const float4*)(At + kk * 68 + ty * 4);
        float4 b = *(const float4*)(Bt + kk * 68 + tx * 4);
        float av[4] = {a.x, a.y, a.z, a.w};
        float bv[4] = {b.x, b.y, b.z, b.w};
#pragma unroll
        for (int r = 0; r < 4; ++r)
#pragma unroll
            for (int s = 0; s < 4; ++s) acc[r][s] += av[r] * bv[s];
    }
}
__device__ __forceinline__ void mm_task(
    const float* aSrc, int aLd, int aRow, int aRowMax, int aCol, int aRowStep, int aColStep,
    const float* bSrc, int bLd, int bRow, int bRowMax, int bCol, int bRowStep, int bColStep,
    bool bTrans, int k0, int k1,
    float acc[4][4], float* smA, float* smB, int t, int tx, int ty)
{
    float4 ra[4], rb[4];
    fetch4(ra, aSrc, aLd, aRow + k0 * aRowStep, aRowMax, aCol + k0 * aColStep, t);
    fetch4(rb, bSrc, bLd, bRow + k0 * bRowStep, bRowMax, bCol + k0 * bColStep, t);
    stT(smA, ra, t);
    if (bTrans) stT(smB, rb, t); else stN(smB, rb, t);
    __syncthreads();
    for (int kt = k0; kt < k1; ++kt) {
        if (kt + 1 < k1) {
            fetch4(ra, aSrc, aLd, aRow + (kt + 1) * aRowStep, aRowMax, aCol + (kt + 1) * aColStep, t);
            fetch4(rb, bSrc, bLd, bRow + (kt + 1) * bRowStep, bRowMax, bCol + (kt + 1) * bColStep, t);
        }
        gemm16(smA, smB, acc, tx, ty);
        __syncthreads();
        if (kt + 1 < k1) {
            stT(smA, ra, t);
            if (bTrans) stT(smB, rb, t); else stN(smB, rb, t);
        }
        __syncthreads();
    }
}

// ========== TRI0: 64x64 diag trtri, 1 wave/block, lane j = column j, x[64] static (grid 16) ==========
__global__ __launch_bounds__(64) void k_tri0(const float* td, const float* tl, float* Wbuf) {
    __shared__ __align__(16) float smem[4416];   // LT [64][68] + dinv [64]
    WS_DECL
    const int t = threadIdx.x;   // lane = column j
    int b0 = blockIdx.x * NB;
    float* LT   = smem;          // LT[i*68 + m] = L[m][i] (0 for m <= i)
    float* dinv = smem + 4352;
    for (int idx = t; idx < 64 * 64; idx += 64) {
        int m = idx >> 6, i = idx & 63;
        LT[i * 68 + m] = (m > i) ? tl[(size_t)(b0 + m) * Dk + b0 + i] : 0.f;
    }
    dinv[t] = 1.f / fabsf(td[b0 + t]);
    __syncthreads();
    const int j = t;
    float r[64];
#pragma unroll
    for (int m = 0; m < 64; ++m) r[m] = (m == j) ? 1.f : 0.f;
#pragma unroll
    for (int i = 0; i < 64; ++i) {
        float x = r[i] * dinv[i];
        r[i] = x;
#pragma unroll
        for (int g = (i >> 2); g < 16; ++g) {
            float4 lt = *(const float4*)&LT[i * 68 + g * 4];
            r[g * 4 + 0] -= lt.x * x;
            r[g * 4 + 1] -= lt.y * x;
            r[g * 4 + 2] -= lt.z * x;
            r[g * 4 + 3] -= lt.w * x;
        }
    }
#pragma unroll
    for (int i = 0; i < 64; ++i)
        W[(size_t)(b0 + i) * Dk + b0 + j] = r[i];
}

// ========== P0: stats, logdet, zeros (Mbuf/QM/Yo32), qno, Y-splits (grid 267) ==========
__global__ __launch_bounds__(256) void k_p0(const float* qx, const int* labels,
                                            const float* mvec, const float* kappa,
                                            const float* nu, const float* td,
                                            float* Wbuf) {
    __shared__ __align__(16) float sX[512];
    WS_DECL
    float* Yo32 = Wbuf;
    const int t = threadIdx.x;
    const int lane = t & 63, wv = t >> 6;
    const int tau = blockIdx.x;

    if (tau == 0) {
        int* scnt = (int*)sX;
        if (t < Ck) scnt[t] = 0;
        __syncthreads();
        for (int n = t; n < Nk; n += 256) {
            int l = labels[n];
            int pos = atomicAdd(&scnt[l], 1);
            cidx[l * Nk + pos] = n;
        }
        __syncthreads();
        if (t < Ck) {
            float kap = fabsf(kappa[0]) + 1e-6f;
            float nu_ = fmaxf(nu[0], (float)(Dk - 1) + 1e-6f);
            float Njf = (float)scnt[t];
            float kN = kap + Njf;
            if (t == 0) { cons[CO_KAPPA] = kap; cons[CO_NU] = nu_; }
            cons[CO_NJ + t] = Njf;
            cons[CO_KN + t] = kN;
            cons[CO_SCALE + t] = (kN + 1.0f) / ((nu_ + Njf - (float)Dk + 1.0f) * kN);
            float common = nu_ + Njf + 1.0f - (float)Dk;
            cons[CO_COMMON + t] = common;
            cons[CO_COEF + t] = 0.5f * (common + (float)Dk);
            cons[CO_BIASA + t] = lgammaf(0.5f * (common + (float)Dk)) - lgammaf(0.5f * common)
                                 - 0.5f * (float)Dk * logf(common);
        }
    } else if (tau == 1) {
        float s = 0.f;
        for (int i = t; i < Dk; i += 256) s += logf(fabsf(td[i]));
        s = wave_red(s);
        if (lane == 0) sX[wv] = s;
        __syncthreads();
        if (t == 0) extraf[0] = 2.f * (sX[0] + sX[1] + sX[2] + sX[3]);
    } else if (tau < 5) {          // zero Mbuf (32*1224 = 39168)
        int base = (tau - 2) * 13056;
        for (int i = t; i < 13056 && base + i < 39168; i += 256) Mbuf[base + i] = 0.f;
    } else if (tau == 5) {         // zero mun2o, gmm, QM
        if (t < 32) { mun2o[t] = 0.f; gmm[t] = 0.f; }
        for (int i = t; i < 8192; i += 256)
            ((float4*)QM)[i] = make_float4(0, 0, 0, 0);
    } else if (tau < 70) {         // qno (16 rows/task)
        int rbase = (tau - 6) * 16;
        for (int j2 = wv; j2 < 16; j2 += 4) {
            const float* row = qx + (size_t)(rbase + j2) * Dk;
            float s = 0.f;
            for (int d = lane; d < Dk; d += 64) { float v = row[d]; s += v * v; }
            s = wave_red(s);
            if (lane == 0) qno[rbase + j2] = s;
        }
    } else if (tau < 134) {        // query rows -> bf16x3 splits (rows 0..1023)
        int rbase = (tau - 70) * 16;
        for (int j2 = 0; j2 < 16; ++j2) {
            int r = rbase + j2;
            float4 v = ((const float4*)(qx + (size_t)r * Dk))[t];
            split_store4(sYh, sYm, sYl, (size_t)r * 1024 + (size_t)t * 4, v);
        }
    } else if (tau == 134) {       // m row (2080) -> splits
        float4 v = ((const float4*)mvec)[t];
        split_store4(sYh, sYm, sYl, (size_t)2080 * 1024 + (size_t)t * 4, v);
    } else {                       // zero Yo32 (2112 rows, 16/task): tau 135..266
        int rbase = (tau - 135) * 16;
        for (int j2 = 0; j2 < 16; ++j2)
            ((float4*)(Yo32 + (size_t)(rbase + j2) * 1024))[t] = make_float4(0, 0, 0, 0);
    }
}

// ========== P1: mu (+splits +mun2o), support split-copy, trtri level-1 (grid 200) ==========
__global__ __launch_bounds__(256) void k_p1(const float* sx, const float* mvec,
                                            const float* tl, float* Wbuf) {
    __shared__ __align__(16) float smem[8704];
    WS_DECL
    const int t = threadIdx.x;
    const int lane = t & 63, wv = t >> 6;
    const int tau = blockIdx.x;
    if (tau < 128) {
        float* sX = smem;
        int c = tau >> 2;
        int d = ((tau & 3) << 8) + t;
        int Nj = (int)cons[CO_NJ + c];
        float kap = cons[CO_KAPPA], kN = cons[CO_KN + c];
        float acc = 0.f;
        for (int s = 0; s < Nj; ++s) acc += sx[(size_t)cidx[c * Nk + s] * Dk + d];
        float muv = (kap * mvec[d] + acc) / kN;
        size_t o = (size_t)(2048 + c) * 1024 + d;
        ushort h, m_, l_;
        split1(muv, h, m_, l_);
        sYh[o] = h; sYm[o] = m_; sYl[o] = l_;
        float s2 = wave_red(muv * muv);
        if (lane == 0) sX[wv] = s2;
        __syncthreads();
        if (t == 0) atomicAdd(&mun2o[c], sX[0] + sX[1] + sX[2] + sX[3]);
    } else if (tau < 192) {
        int rbase = (tau - 128) * 16;
        for (int j = 0; j < 16; ++j) {
            int n = rbase + j;
            int srcrow = cidx[(n >> 5) * Nk + (n & 31)];
            float4 v = ((const float4*)(sx + (size_t)srcrow * Dk))[t];
            split_store4(sYh, sYm, sYl, (size_t)(1024 + n) * 1024 + (size_t)t * 4, v);
        }
    } else {
        // trtri level-1: merged T = B*Ainv then -Cinv*T, local 128-block
        float* smA = smem;
        float* smB = smem + 4352;
        const int tx = t & 15, ty = t >> 4;
        const int BIG = 1 << 30;
        int pb = (tau - 192) * 128;
        float acc[4][4] = {};
        mm_task(tl, Dk, pb + 64, BIG, pb, 0, NB,
                W, Dk, pb, BIG, pb, NB, 0, false, 0, 1,
                acc, smA, smB, t, tx, ty);
        {
            float4 ra[4];
            fetch4(ra, W, Dk, pb + 64, BIG, pb + 64, t);
#pragma unroll
            for (int r = 0; r < 4; ++r)
#pragma unroll
                for (int s = 0; s < 4; ++s)
                    smB[(ty * 4 + r) * 68 + tx * 4 + s] = acc[r][s];
            stT(smA, ra, t);
        }
        __syncthreads();
        float acc2[4][4] = {};
        gemm16(smA, smB, acc2, tx, ty);
        __syncthreads();
#pragma unroll
        for (int r = 0; r < 4; ++r)
#pragma unroll
            for (int s = 0; s < 4; ++s)
                W[(size_t)(pb + 64 + ty * 4 + r) * Dk + pb + tx * 4 + s] = -acc2[r][s];
    }
}

// ========== trtri level l phase A: T = B * Ainv ==========
__global__ __launch_bounds__(256) void k_tr_a(const float* tl, float* Wbuf, int h, int ht) {
    __shared__ __align__(16) float smem[8704];
    float* smA = smem;
    float* smB = smem + 4352;
    WS_DECL
    const int t = threadIdx.x;
    const int tx = t & 15, ty = t >> 4;
    const int BIG = 1 << 30;
    int tau = blockIdx.x;
    int p = tau / (ht * ht), rr = tau % (ht * ht);
    int i = rr / ht, j = rr % ht;
    int pb = p * 2 * h;
    float acc[4][4] = {};
    mm_task(tl, Dk, pb + h + i * NB, BIG, pb, 0, NB,
            W, Dk, pb, BIG, pb + j * NB, NB, 0, false, 0, ht,
            acc, smA, smB, t, tx, ty);
    float* Tp = Tb + (size_t)p * h * h;
#pragma unroll
    for (int r = 0; r < 4; ++r)
#pragma unroll
        for (int s = 0; s < 4; ++s)
            Tp[(size_t)(i * NB + ty * 4 + r) * h + j * NB + tx * 4 + s] = acc[r][s];
}

// ========== trtri level l phase B: W_off = -Cinv * T ==========
__global__ __launch_bounds__(256) void k_tr_b(float* Wbuf, int h, int ht) {
    __shared__ __align__(16) float smem[8704];
    float* smA = smem;
    float* smB = smem + 4352;
    WS_DECL
    const int t = threadIdx.x;
    const int tx = t & 15, ty = t >> 4;
    const int BIG = 1 << 30;
    int tau = blockIdx.x;
    int p = tau / (ht * ht), rr = tau % (ht * ht);
    int i = rr / ht, j = rr % ht;
    int pb = p * 2 * h;
    const float* Tp = Tb + (size_t)p * h * h;
    float acc[4][4] = {};
    mm_task(W, Dk, pb + h + i * NB, BIG, pb + h, 0, NB,
            Tp, h, 0, BIG, j * NB, NB, 0, false, 0, ht,
            acc, smA, smB, t, tx, ty);
#pragma unroll
    for (int r = 0; r < 4; ++r)
#pragma unroll
        for (int s = 0; s < 4; ++s)
            W[(size_t)(pb + h + i * NB + ty * 4 + r) * Dk + pb + j * NB + tx * 4 + s] = -acc[r][s];
}

// ========== CVTW: 3-way bf16 split of W, lower-tri masked (grid 256) ==========
__global__ __launch_bounds__(256) void k_cvtw(float* Wbuf) {
    WS_DECL
    const int t = threadIdx.x;
#pragma unroll
    for (int u = 0; u < 4; ++u) {
        unsigned g = blockIdx.x * 1024u + u * 256u + t;   // float4 index
        int row = g >> 8, col4 = (g & 255) * 4;
        float4 v = ((const float4*)W)[g];
        if (col4 + 0 > row) v.x = 0.f;
        if (col4 + 1 > row) v.y = 0.f;
        if (col4 + 2 > row) v.z = 0.f;
        if (col4 + 3 > row) v.w = 0.f;
        split_store4(sWh, sWm, sWl, (size_t)g * 4, v);
    }
}

// ========== YG: Yo32 += Y * W^T, 64x128 tiles, uniform <=8-kstep chunks (grid 660) ==========
__global__ __launch_bounds__(256) void k_yg(float* Wbuf) {
    __shared__ __align__(16) ushort lds[LDS_HW3];
    WS_DECL
    float* Yo32 = Wbuf;
    const int t = threadIdx.x;
    int e = blockIdx.x;
    int q = e / 33, rt = e % 33;
    int jt2, kc;
    if (q < 4)       { jt2 = 7; kc = q; }
    else if (q < 8)  { jt2 = 6; kc = q - 4; }
    else if (q < 11) { jt2 = 5; kc = q - 8; }
    else if (q < 14) { jt2 = 4; kc = q - 11; }
    else if (q < 16) { jt2 = 3; kc = q - 14; }
    else if (q < 18) { jt2 = 2; kc = q - 16; }
    else if (q == 18){ jt2 = 1; kc = 0; }
    else             { jt2 = 0; kc = 0; }
    int ksteps = min(8, 4 * (jt2 + 1) - kc * 8);
    f32x4 acc[2][4] = {};
    tile_gemm64(lds, acc, sYh, sYm, sYl, rt * 64, 2081,
                sWh, sWm, sWl, jt2 * 128, kc * 8, ksteps, t);
    const int w = t >> 6, lr = t & 15, lk = (t >> 4) & 3;
#pragma unroll
    for (int rf = 0; rf < 2; ++rf)
#pragma unroll
        for (int cf = 0; cf < 4; ++cf)
#pragma unroll
            for (int r = 0; r < 4; ++r) {
                int grow = rt * 64 + (w >> 1) * 32 + rf * 16 + lk * 4 + r;
                if (grow < NROWSV)
                    atomicAdd(&Yo32[(size_t)grow * 1024 + jt2 * 128 + (w & 1) * 64 + cf * 16 + lr],
                              acc[rf][cf][r]);
            }
}

// ========== CVTO: Yo32 -> bf16x3 splits; zero P rows under it (grid 528) ==========
__global__ __launch_bounds__(256) void k_cvto(float* Wbuf) {
    WS_DECL
    float* Yo32 = Wbuf;
    const int t = threadIdx.x;
    int rbase = blockIdx.x * 4;
#pragma unroll
    for (int j = 0; j < 4; ++j) {
        int r = rbase + j;
        float4 v = ((const float4*)(Yo32 + (size_t)r * 1024))[t];
        split_store4(sOh, sOm, sOl, (size_t)r * 1024 + (size_t)t * 4, v);
    }
    if (rbase < 1088) {
#pragma unroll
        for (int j = 0; j < 4; ++j)
            ((float4*)(Yo32 + (size_t)(rbase + j) * 1024))[t] = make_float4(0, 0, 0, 0);
    }
}

// ========== P4M: P += Yo_s*Yo_q^T (544, 64-row tiles) + QM += mu*qx^T (32) (grid 576) ==========
__global__ __launch_bounds__(256) void k_p4m(float* Wbuf) {
    __shared__ __align__(16) ushort lds[LDS_HW3];
    WS_DECL
    const int t = threadIdx.x;
    int e = blockIdx.x;
    const int w = t >> 6, lr = t & 15, lk = (t >> 4) & 3;
    f32x4 acc[2][4] = {};
    if (e < 544) {
        int tile = e >> 2, kc = e & 3;    // 136 tiles (17 mt x 8 qt2) x 4 k-chunks
        int mt = tile >> 3, qt2 = tile & 7;
        tile_gemm64(lds, acc, sOh, sOm, sOl, 1024 + mt * 64, 2081,
                    sOh, sOm, sOl, qt2 * 128, kc * 8, 8, t);
#pragma unroll
        for (int rf = 0; rf < 2; ++rf)
#pragma unroll
            for (int cf = 0; cf < 4; ++cf)
#pragma unroll
                for (int r = 0; r < 4; ++r) {
                    int n = mt * 64 + (w >> 1) * 32 + rf * 16 + lk * 4 + r;
                    if (n < Nk + Ck + 1)
                        atomicAdd(&P[(size_t)n * 1024 + qt2 * 128 + (w & 1) * 64 + cf * 16 + lr],
                                  acc[rf][cf][r]);
                }
    } else {
        int f = e - 544;
        int qt2 = f >> 2, kc = f & 3;
        tile_gemm64(lds, acc, sYh, sYm, sYl, 2048, 2080,
                    sYh, sYm, sYl, qt2 * 128, kc * 8, 8, t);
#pragma unroll
        for (int rf = 0; rf < 2; ++rf)
#pragma unroll
            for (int cf = 0; cf < 4; ++cf)
#pragma unroll
                for (int r = 0; r < 4; ++r) {
                    int rq = (w >> 1) * 32 + rf * 16 + lk * 4 + r;
                    if (rq < 32)
                        atomicAdd(&QM[(size_t)rq * 1024 + qt2 * 128 + (w & 1) * 64 + cf * 16 + lr],
                                  acc[rf][cf][r]);
                }
    }
}

// ========== GRAM: per-class 34x34 gram (128 tasks) + qny (64 tasks) (grid 192) ==========
__global__ __launch_bounds__(256) void k_gram(float* Wbuf) {
    __shared__ __align__(16) float smA[34 * 68];
    WS_DECL
    const int t = threadIdx.x;
    const int lane = t & 63, wv = t >> 6;
    const int tau = blockIdx.x;
    if (tau < 128) {
        int c = tau >> 2, kc = tau & 3;
        float accg[5];
        int iu[5], ju[5];
#pragma unroll
        for (int u = 0; u < 5; ++u) {
            int e = t + u * 256;
            iu[u] = e / 34; ju[u] = e - iu[u] * 34;
            accg[u] = 0.f;
        }
        for (int kt = kc * 4; kt < kc * 4 + 4; ++kt) {
            for (int e2 = t; e2 < 34 * NB; e2 += 256) {
                int i = e2 >> 6, k = e2 & 63;
                int yr = (i < 32) ? (Qk + c * 32 + i) : ((i == 32) ? (Qk + Nk + c) : (Qk + Nk + Ck));
                size_t o = (size_t)yr * 1024 + kt * NB + k;
                smA[i * 68 + k] = bf2f(sOh[o]) + bf2f(sOm[o]) + bf2f(sOl[o]);
            }
            __syncthreads();
#pragma unroll
            for (int u = 0; u < 5; ++u) {
                int e = t + u * 256;
                if (e < 1156) {
                    float s = 0.f;
                    for (int k = 0; k < NB; ++k) s += smA[iu[u] * 68 + k] * smA[ju[u] * 68 + k];
                    accg[u] += s;
                }
            }
            __syncthreads();
        }
#pragma unroll
        for (int u = 0; u < 5; ++u) {
            int e = t + u * 256;
            if (e < 1156)
                atomicAdd(&Mbuf[c * 1224 + iu[u] * 36 + ju[u]], accg[u]);
        }
    } else {
        int rbase = (tau - 128) * 16;
        for (int j = wv; j < 16; j += 4) {
            size_t ro = (size_t)(rbase + j) * 1024;
            float s = 0.f;
            for (int d = lane; d < Dk; d += 64) {
                size_t o = ro + d;
                float v = bf2f(sOh[o]) + bf2f(sOm[o]) + bf2f(sOl[o]);
                s += v * v;
            }
            s = wave_red(s);
            if (lane == 0) qny[rbase + j] = s;
        }
    }
}

// ========== P5: per-class 34x34 Gauss-Jordan inverse + bias (grid 32, 64 thr) ==========
__global__ __launch_bounds__(64) void k_p5(float* Wbuf) {
    __shared__ __align__(16) float A[34 * 36];   // stride 36 -> 16B-aligned rows
    WS_DECL
    const int t = threadIdx.x;
    const int c = blockIdx.x;
    float kN = cons[CO_KN + c], kap = cons[CO_KAPPA];
    for (int e = t; e < 34 * 34; e += 64) {
        int i = e / 34, j = e - i * 34;
        A[i * 36 + j] = Mbuf[c * 1224 + i * 36 + j];
    }
    __syncthreads();
    if (t == 0) {
        gmm[c] = A[32 * 36 + 32];
        A[32 * 36 + 32] += -1.f / kN;
        A[33 * 36 + 33] += 1.f / kap;
    }
    if (t < 32) A[t * 36 + t] += 1.f;
    __syncthreads();
    float ldacc = 0.f;
    for (int j = 0; j < 34; ++j) {
        float piv = A[j * 36 + j];
        float pinv = 1.f / piv;
        if (t == 0) ldacc += logf(fabsf(piv));
        if (t < 34 && t != j) A[j * 36 + t] *= pinv;   // scale pivot row
        __syncthreads();
        if (t < 34) {
            if (t != j) {
                float f = A[t * 36 + j];
                float4* rowT = (float4*)(A + t * 36);
                const float4* rowJ = (const float4*)(A + j * 36);
#pragma unroll
                for (int k4 = 0; k4 < 8; ++k4) {
                    float4 rv = rowT[k4], pv = rowJ[k4];
                    rv.x -= f * pv.x; rv.y -= f * pv.y;
                    rv.z -= f * pv.z; rv.w -= f * pv.w;
                    rowT[k4] = rv;
                }
                A[t * 36 + 32] -= f * A[j * 36 + 32];
                A[t * 36 + 33] -= f * A[j * 36 + 33];
                A[t * 36 + j] = -f * pinv;            // column j (overwrites racy k=j slot)
            } else {
                A[j * 36 + j] = pinv;
            }
        }
        __syncthreads();
    }
    for (int e = t; e < 34 * 34; e += 64) {
        int i = e / 34, j = e - i * 34;
        Minv[c * 1224 + i * 36 + j] = A[i * 36 + j];
    }
    if (t == 0) {
        float scale = cons[CO_SCALE + c];
        float logdet = (float)Dk * logf(scale) + extraf[0] + logf(kN) + logf(kap) + ldacc;
        cons[CO_BIASF + c] = cons[CO_BIASA + c] - 0.5f * logdet;
    }
}

// ========== P6: epilogue, (qt, c) tasks (grid 512) ==========
__global__ __launch_bounds__(256) void k_p6(float* Wbuf, float* out) {
    __shared__ __align__(16) float smem[3904];
    float* Mi  = smem;          // stride 35 (1190)
    float* wL  = smem + 1200;   // stride 68 (2312)
    float* gsm = smem + 3520;   // 34
    float* red = smem + 3520 + 128;  // 256
    WS_DECL
    const int t = threadIdx.x;
    const int tau = blockIdx.x;
    int qt = tau >> 5, c = tau & 31;
    for (int e = t; e < 34 * 34; e += 256) {
        int i = e / 34, j = e - i * 34;
        Mi[i * 35 + j] = Minv[c * 1224 + i * 36 + j];
    }
    if (t < 34)
        gsm[t] = (t < 32) ? Mbuf[c * 1224 + t * 36 + 32]
                          : ((t == 32) ? gmm[c] : Mbuf[c * 1224 + 33 * 36 + 32]);
    __syncthreads();
    for (int e = t; e < 34 * NB; e += 256) {
        int i = e >> 6, qq = e & 63;
        int prow = (i < 32) ? (c * 32 + i) : ((i == 32) ? (Nk + c) : (Nk + Ck));
        wL[i * 68 + qq] = P[(size_t)prow * Qk + qt * NB + qq] - gsm[i];
    }
    __syncthreads();
    {
        int q = t & 63, part = t >> 6;
        int start = (part < 2) ? part * 9 : 18 + (part - 2) * 8;
        int cnt = (part < 2) ? 9 : 8;
        float partial = 0.f;
        for (int i = start; i < start + cnt; ++i) {
            float v = 0.f;
            for (int j = 0; j < 34; ++j) v += Mi[i * 35 + j] * wL[j * 68 + q];
            partial += v * wL[i * 68 + q];
        }
        red[part * 64 + q] = partial;
    }
    __syncthreads();
    if (t < 64) {
        int q = t;
        float quad = red[q] + red[64 + q] + red[128 + q] + red[192 + q];
        int qg = qt * NB + q;
        float w32 = wL[32 * 68 + q];
        float ydist2 = qny[qg] - 2.f * w32 - gmm[c];
        float dd = qno[qg] + mun2o[c] - 2.f * QM[(size_t)c * Qk + qg];
        float scale = cons[CO_SCALE + c], common = cons[CO_COMMON + c];
        float dist = (1.f - REGP) / scale * (ydist2 - quad) + REGP * dd;
        out[(size_t)qg * Ck + c] = cons[CO_BIASF + c] - cons[CO_COEF + c] * log1pf(dist / common);
    }
}

extern "C" void kernel_launch(void* const* d_in, const int* in_sizes, int n_in,
                              void* d_out, int out_size, void* d_ws, size_t ws_size,
                              hipStream_t stream) {
    const float* sx = (const float*)d_in[0];
    const float* qx = (const float*)d_in[1];
    const int* labels = (const int*)d_in[2];
    const float* mvec = (const float*)d_in[3];
    const float* kappa = (const float*)d_in[4];
    const float* nu = (const float*)d_in[5];
    const float* td = (const float*)d_in[6];
    const float* tl = (const float*)d_in[7];
    float* W = (float*)d_ws;
    float* out = (float*)d_out;

    hipLaunchKernelGGL(k_tri0, dim3(16), dim3(64), 0, stream, td, tl, W);
    hipLaunchKernelGGL(k_p0, dim3(267), dim3(256), 0, stream,
                       qx, labels, mvec, kappa, nu, td, W);
    hipLaunchKernelGGL(k_p1, dim3(200), dim3(256), 0, stream, sx, mvec, tl, W);
    for (int l = 2; l <= 4; ++l) {
        int h = 32 << l, ht = h >> 6, pairs = 16 >> l;
        int nt = pairs * ht * ht;
        hipLaunchKernelGGL(k_tr_a, dim3(nt), dim3(256), 0, stream, tl, W, h, ht);
        hipLaunchKernelGGL(k_tr_b, dim3(nt), dim3(256), 0, stream, W, h, ht);
    }
    hipLaunchKernelGGL(k_cvtw, dim3(256), dim3(256), 0, stream, W);
    hipLaunchKernelGGL(k_yg, dim3(660), dim3(256), 0, stream, W);
    hipLaunchKernelGGL(k_cvto, dim3(528), dim3(256), 0, stream, W);
    hipLaunchKernelGGL(k_p4m, dim3(576), dim3(256), 0, stream, W);
    hipLaunchKernelGGL(k_gram, dim3(192), dim3(256), 0, stream, W);
    hipLaunchKernelGGL(k_p5, dim3(32), dim3(64), 0, stream, W);
    hipLaunchKernelGGL(k_p6, dim3(512), dim3(256), 0, stream, W, out);
}

// Round 16
// 344.022 us; speedup vs baseline: 1.1418x; 1.1418x over previous
//
#include <hip/hip_runtime.h>
#include <math.h>

#define Dk 1024
#define Ck 32
#define Nk 1024
#define Qk 1024
#define REGP 0.5f
#define NB 64
#define NROWSV (Qk + Nk + Ck + 1)   // 2081 rows: queries, sorted support, mus, m

// consts layout (floats)
#define CO_KAPPA 0
#define CO_NU    1
#define CO_NJ    2
#define CO_KN    34
#define CO_SCALE 66
#define CO_COMMON 98
#define CO_COEF  130
#define CO_BIASA 162
#define CO_BIASF 200

// workspace offsets (floats). Offset 0 = Yo32 (fp32 accum), later aliased by P.
#define O_P    0u
#define O_W    2162688u
#define O_T    3211264u
#define O_MU   3473408u
#define O_QM   3506176u
#define O_MB   3538944u
#define O_MI   3578112u
#define O_QNY  3617280u
#define O_QNO  3618304u
#define O_MUN  3619328u
#define O_GMM  3619360u
#define O_EX   3619392u
#define O_CONS 3619408u
#define O_CIDX 3619664u
// bf16 split matrices (ushort storage, offsets in floats)
#define O_YH   3652432u
#define O_YM   4733776u
#define O_YL   5815120u
#define O_WH   6896464u
#define O_WM   7420752u
#define O_WL   7945040u
#define O_OH   8469328u
#define O_OM   9550672u
#define O_OL   10632016u
// total = 11,713,360 floats = 46.9 MB

#define WS_DECL \
    float* P     = Wbuf + O_P;    (void)P; \
    float* W     = Wbuf + O_W;    (void)W; \
    float* Tb    = Wbuf + O_T;    (void)Tb; \
    float* QM    = Wbuf + O_QM;   (void)QM; \
    float* Mbuf  = Wbuf + O_MB;   (void)Mbuf; \
    float* Minv  = Wbuf + O_MI;   (void)Minv; \
    float* qny   = Wbuf + O_QNY;  (void)qny; \
    float* qno   = Wbuf + O_QNO;  (void)qno; \
    float* mun2o = Wbuf + O_MUN;  (void)mun2o; \
    float* gmm   = Wbuf + O_GMM;  (void)gmm; \
    float* extraf= Wbuf + O_EX;   (void)extraf; \
    float* cons  = Wbuf + O_CONS; (void)cons; \
    int*   cidx  = (int*)(Wbuf + O_CIDX); (void)cidx; \
    ushort* sYh = (ushort*)(Wbuf + O_YH); (void)sYh; \
    ushort* sYm = (ushort*)(Wbuf + O_YM); (void)sYm; \
    ushort* sYl = (ushort*)(Wbuf + O_YL); (void)sYl; \
    ushort* sWh = (ushort*)(Wbuf + O_WH); (void)sWh; \
    ushort* sWm = (ushort*)(Wbuf + O_WM); (void)sWm; \
    ushort* sWl = (ushort*)(Wbuf + O_WL); (void)sWl; \
    ushort* sOh = (ushort*)(Wbuf + O_OH); (void)sOh; \
    ushort* sOm = (ushort*)(Wbuf + O_OM); (void)sOm; \
    ushort* sOl = (ushort*)(Wbuf + O_OL); (void)sOl;

typedef __attribute__((ext_vector_type(8))) __bf16 bf16x8;
typedef __attribute__((ext_vector_type(4))) float f32x4;

#define MFMA(a, b, c) __builtin_amdgcn_mfma_f32_16x16x32_bf16(a, b, c, 0, 0, 0)

__device__ __forceinline__ ushort f2bf(float x) {
    unsigned u = __float_as_uint(x);
    return (ushort)((u + 0x7FFFu + ((u >> 16) & 1u)) >> 16);
}
__device__ __forceinline__ float bf2f(ushort h) {
    return __uint_as_float(((unsigned)h) << 16);
}
__device__ __forceinline__ void split1(float x, ushort& h, ushort& m, ushort& l) {
    h = f2bf(x);
    float r1 = x - bf2f(h);
    m = f2bf(r1);
    l = f2bf(r1 - bf2f(m));
}
__device__ __forceinline__ void split_store4(ushort* ph, ushort* pm, ushort* pl,
                                             size_t o, float4 v) {
    float vv[4] = {v.x, v.y, v.z, v.w};
    ushort4 H, M, L;
    ushort* Hp = (ushort*)&H; ushort* Mp = (ushort*)&M; ushort* Lp = (ushort*)&L;
#pragma unroll
    for (int c = 0; c < 4; ++c) split1(vv[c], Hp[c], Mp[c], Lp[c]);
    *(ushort4*)(ph + o) = H;
    *(ushort4*)(pm + o) = M;
    *(ushort4*)(pl + o) = L;
}

__device__ __forceinline__ float wave_red(float s) {
#pragma unroll
    for (int o = 32; o > 0; o >>= 1) s += __shfl_down(s, o, 64);
    return s;
}

// ---------- bf16x3 MFMA tiles v3: B-only LDS, A direct-global, 2x2 waves of 64x64 ----------
// LDS halfword offsets: B comps [3][128][40] (80B row stride, 2-way bank max).
#define LDSB3(c, r, k8) ((c) * 5120 + (r) * 40 + (k8))
#define LDS_HW3 15360   // 30720 B

__device__ __forceinline__ void b_fetch3(bf16x8* rb,
                                         const ushort* Bh, const ushort* Bm, const ushort* Bl,
                                         int bRow0, int kcol, int t) {
#pragma unroll
    for (int u = 0; u < 6; ++u) {
        int comp = u >> 1;
        int idx = ((u & 1) << 8) + t;     // 0..511 : row=idx>>2, kg=idx&3
        int row = idx >> 2, kg = idx & 3;
        const ushort* Bs = (comp == 0) ? Bh : ((comp == 1) ? Bm : Bl);
        rb[u] = *(const bf16x8*)(Bs + (size_t)(bRow0 + row) * 1024 + kcol + kg * 8);
    }
}
__device__ __forceinline__ void b_store3(ushort* lds, const bf16x8* rb, int t) {
#pragma unroll
    for (int u = 0; u < 6; ++u) {
        int comp = u >> 1;
        int idx = ((u & 1) << 8) + t;
        int row = idx >> 2, kg = idx & 3;
        *(bf16x8*)(lds + LDSB3(comp, row, kg * 8)) = rb[u];
    }
}
__device__ __forceinline__ void a_fetch3(bf16x8 af[4][3],
                                         const ushort* Ah, const ushort* Am, const ushort* Al,
                                         int arowT, int aRowMax, int kcol, int lk) {
    bf16x8 z = {};
#pragma unroll
    for (int rf = 0; rf < 4; ++rf) {
        int gr = arowT + rf * 16;
        bool ok = gr < aRowMax;
#pragma unroll
        for (int c = 0; c < 3; ++c) {
            const ushort* As = (c == 0) ? Ah : ((c == 1) ? Am : Al);
            af[rf][c] = ok ? *(const bf16x8*)(As + (size_t)gr * 1024 + kcol + lk * 8) : z;
        }
    }
}

// wave w (2x2): rows (w>>1)*64 (4 frags) x cols (w&1)*64 (4 frags); 6-term bf16x3.
__device__ __forceinline__ void tile_compute3(const ushort* lds, f32x4 acc[4][4],
                                              bf16x8 af[4][3], int bcol0, int lr, int lk) {
#pragma unroll
    for (int cf = 0; cf < 4; ++cf) {
        int brow = bcol0 + cf * 16 + lr;
        bf16x8 bh = *(const bf16x8*)(lds + LDSB3(0, brow, lk * 8));
        bf16x8 bm = *(const bf16x8*)(lds + LDSB3(1, brow, lk * 8));
        bf16x8 bl = *(const bf16x8*)(lds + LDSB3(2, brow, lk * 8));
#pragma unroll
        for (int rf = 0; rf < 4; ++rf) {
            f32x4 a = acc[rf][cf];
            a = MFMA(af[rf][0], bh, a);
            a = MFMA(af[rf][0], bm, a);
            a = MFMA(af[rf][1], bh, a);
            a = MFMA(af[rf][0], bl, a);
            a = MFMA(af[rf][2], bh, a);
            a = MFMA(af[rf][1], bm, a);
            acc[rf][cf] = a;
        }
    }
}

__device__ __forceinline__ void tile_gemm3(
    ushort* lds, f32x4 acc[4][4],
    const ushort* Ah, const ushort* Am, const ushort* Al, int aRow0, int aRowMax,
    const ushort* Bh, const ushort* Bm, const ushort* Bl, int bRow0,
    int kbase, int ksteps, int t)
{
    const int w = t >> 6, lr = t & 15, lk = (t >> 4) & 3;
    const int arowT = aRow0 + (w >> 1) * 64 + lr;
    const int bcol0 = (w & 1) * 64;
    bf16x8 rb[6], afc[4][3], afn[4][3];
    b_fetch3(rb, Bh, Bm, Bl, bRow0, kbase * 32, t);
    a_fetch3(afc, Ah, Am, Al, arowT, aRowMax, kbase * 32, lk);
    b_store3(lds, rb, t);
    __syncthreads();
    for (int kt = 0; kt < ksteps; ++kt) {
        if (kt + 1 < ksteps) {
            b_fetch3(rb, Bh, Bm, Bl, bRow0, (kbase + kt + 1) * 32, t);
            a_fetch3(afn, Ah, Am, Al, arowT, aRowMax, (kbase + kt + 1) * 32, lk);
        }
        tile_compute3(lds, acc, afc, bcol0, lr, lk);
        __syncthreads();
        if (kt + 1 < ksteps) {
            b_store3(lds, rb, t);
#pragma unroll
            for (int rf = 0; rf < 4; ++rf)
#pragma unroll
                for (int c = 0; c < 3; ++c) afc[rf][c] = afn[rf][c];
        }
        __syncthreads();
    }
}

// ---------- fp32 tile-GEMM machinery (trtri chain) ----------
__device__ __forceinline__ void fetch4(float4* reg, const float* src, int ld,
                                       int rowbase, int rowmax, int colbase, int t) {
#pragma unroll
    for (int u = 0; u < 4; ++u) {
        int slot = t + u * 256;
        int r = slot >> 4, c4 = slot & 15;
        int gr = rowbase + r;
        reg[u] = (gr < rowmax) ? *(const float4*)(src + (size_t)gr * ld + colbase + c4 * 4)
                               : make_float4(0.f, 0.f, 0.f, 0.f);
    }
}
__device__ __forceinline__ void stT(float* dst, const float4* reg, int t) {
#pragma unroll
    for (int u = 0; u < 4; ++u) {
        int slot = t + u * 256;
        int r = slot >> 4, c4 = slot & 15;
        dst[(c4 * 4 + 0) * 68 + r] = reg[u].x;
        dst[(c4 * 4 + 1) * 68 + r] = reg[u].y;
        dst[(c4 * 4 + 2) * 68 + r] = reg[u].z;
        dst[(c4 * 4 + 3) * 68 + r] = reg[u].w;
    }
}
__device__ __forceinline__ void stN(float* dst, const float4* reg, int t) {
#pragma unroll
    for (int u = 0; u < 4; ++u) {
        int slot = t + u * 256;
        int r = slot >> 4, c4 = slot & 15;
        *(float4*)(dst + r * 68 + c4 * 4) = reg[u];
    }
}
__device__ __forceinline__ void gemm16(const float* At, const float* Bt,
                                       float acc[4][4], int tx, int ty) {
#pragma unroll 4
    for (int kk = 0; kk < NB; ++kk) {
        float4 a = *(const float4*)(At + kk * 68 + ty * 4);
        float4 b = *(const float4*)(Bt + kk * 68 + tx * 4);
        float av[4] = {a.x, a.y, a.z, a.w};
        float bv[4] = {b.x, b.y, b.z, b.w};
#pragma unroll
        for (int r = 0; r < 4; ++r)
#pragma unroll
            for (int s = 0; s < 4; ++s) acc[r][s] += av[r] * bv[s];
    }
}
__device__ __forceinline__ void mm_task(
    const float* aSrc, int aLd, int aRow, int aRowMax, int aCol, int aRowStep, int aColStep,
    const float* bSrc, int bLd, int bRow, int bRowMax, int bCol, int bRowStep, int bColStep,
    bool bTrans, int k0, int k1,
    float acc[4][4], float* smA, float* smB, int t, int tx, int ty)
{
    float4 ra[4], rb[4];
    fetch4(ra, aSrc, aLd, aRow + k0 * aRowStep, aRowMax, aCol + k0 * aColStep, t);
    fetch4(rb, bSrc, bLd, bRow + k0 * bRowStep, bRowMax, bCol + k0 * bColStep, t);
    stT(smA, ra, t);
    if (bTrans) stT(smB, rb, t); else stN(smB, rb, t);
    __syncthreads();
    for (int kt = k0; kt < k1; ++kt) {
        if (kt + 1 < k1) {
            fetch4(ra, aSrc, aLd, aRow + (kt + 1) * aRowStep, aRowMax, aCol + (kt + 1) * aColStep, t);
            fetch4(rb, bSrc, bLd, bRow + (kt + 1) * bRowStep, bRowMax, bCol + (kt + 1) * bColStep, t);
        }
        gemm16(smA, smB, acc, tx, ty);
        __syncthreads();
        if (kt + 1 < k1) {
            stT(smA, ra, t);
            if (bTrans) stT(smB, rb, t); else stN(smB, rb, t);
        }
        __syncthreads();
    }
}

// ========== P0: stats, logdet, trtri diag, zeros (Mbuf/QM/qny/Yo32), qno, Y-splits (grid 283) ==========
__global__ __launch_bounds__(256) void k_p0(const float* qx, const int* labels,
                                            const float* mvec, const float* kappa,
                                            const float* nu, const float* td,
                                            const float* tl, float* Wbuf) {
    __shared__ __align__(16) float smem[9216];
    float* sX  = smem + 8704;
    WS_DECL
    float* Yo32 = Wbuf;
    const int t = threadIdx.x;
    const int lane = t & 63, wv = t >> 6;
    const int tau = blockIdx.x;

    if (tau == 0) {
        int* scnt = (int*)sX;
        if (t < Ck) scnt[t] = 0;
        __syncthreads();
        for (int n = t; n < Nk; n += 256) {
            int l = labels[n];
            int pos = atomicAdd(&scnt[l], 1);
            cidx[l * Nk + pos] = n;
        }
        __syncthreads();
        if (t < Ck) {
            float kap = fabsf(kappa[0]) + 1e-6f;
            float nu_ = fmaxf(nu[0], (float)(Dk - 1) + 1e-6f);
            float Njf = (float)scnt[t];
            float kN = kap + Njf;
            if (t == 0) { cons[CO_KAPPA] = kap; cons[CO_NU] = nu_; }
            cons[CO_NJ + t] = Njf;
            cons[CO_KN + t] = kN;
            cons[CO_SCALE + t] = (kN + 1.0f) / ((nu_ + Njf - (float)Dk + 1.0f) * kN);
            float common = nu_ + Njf + 1.0f - (float)Dk;
            cons[CO_COMMON + t] = common;
            cons[CO_COEF + t] = 0.5f * (common + (float)Dk);
            cons[CO_BIASA + t] = lgammaf(0.5f * (common + (float)Dk)) - lgammaf(0.5f * common)
                                 - 0.5f * (float)Dk * logf(common);
        }
    } else if (tau == 1) {
        float s = 0.f;
        for (int i = t; i < Dk; i += 256) s += logf(fabsf(td[i]));
        s = wave_red(s);
        if (lane == 0) sX[wv] = s;
        __syncthreads();
        if (t == 0) extraf[0] = 2.f * (sX[0] + sX[1] + sX[2] + sX[3]);
    } else if (tau < 18) {
        // trtri of 64x64 diag block: lane j = column j, register forward substitution.
        int b0 = (tau - 2) * NB;
        for (int idx = t; idx < 64 * 64; idx += 256) {
            int m = idx >> 6, i = idx & 63;
            smem[i * 72 + m] = (m > i) ? tl[(size_t)(b0 + m) * Dk + b0 + i] : 0.f;
        }
        if (t < 64) smem[4608 + t] = 1.f / fabsf(td[b0 + t]);
        __syncthreads();
        if (t < 64) {
            const int j = t;
            float r[64];
#pragma unroll
            for (int m = 0; m < 64; ++m) r[m] = (m == j) ? 1.f : 0.f;
#pragma unroll
            for (int i = 0; i < 64; ++i) {
                float x = r[i] * smem[4608 + i];
                r[i] = x;
#pragma unroll
                for (int g = (i >> 2); g < 16; ++g) {
                    float4 lt = *(const float4*)&smem[i * 72 + g * 4];
                    r[g * 4 + 0] -= lt.x * x;
                    r[g * 4 + 1] -= lt.y * x;
                    r[g * 4 + 2] -= lt.z * x;
                    r[g * 4 + 3] -= lt.w * x;
                }
            }
#pragma unroll
            for (int i = 0; i < 64; ++i)
                W[(size_t)(b0 + i) * Dk + b0 + j] = r[i];
        }
    } else if (tau < 21) {         // zero Mbuf (32*1224 = 39168)
        int base = (tau - 18) * 13056;
        for (int i = t; i < 13056 && base + i < 39168; i += 256) Mbuf[base + i] = 0.f;
    } else if (tau == 21) {        // zero mun2o, gmm, QM, qny
        if (t < 32) { mun2o[t] = 0.f; gmm[t] = 0.f; }
        for (int i = t; i < 8192; i += 256)
            ((float4*)QM)[i] = make_float4(0, 0, 0, 0);
        if (t < 256) ((float4*)qny)[t] = make_float4(0, 0, 0, 0);
    } else if (tau < 86) {         // qno (16 rows/task)
        int rbase = (tau - 22) * 16;
        for (int j2 = wv; j2 < 16; j2 += 4) {
            const float* row = qx + (size_t)(rbase + j2) * Dk;
            float s = 0.f;
            for (int d = lane; d < Dk; d += 64) { float v = row[d]; s += v * v; }
            s = wave_red(s);
            if (lane == 0) qno[rbase + j2] = s;
        }
    } else if (tau < 150) {        // query rows -> bf16x3 splits (rows 0..1023)
        int rbase = (tau - 86) * 16;
        for (int j2 = 0; j2 < 16; ++j2) {
            int r = rbase + j2;
            float4 v = ((const float4*)(qx + (size_t)r * Dk))[t];
            split_store4(sYh, sYm, sYl, (size_t)r * 1024 + (size_t)t * 4, v);
        }
    } else if (tau == 150) {       // m row (2080) -> splits
        float4 v = ((const float4*)mvec)[t];
        split_store4(sYh, sYm, sYl, (size_t)2080 * 1024 + (size_t)t * 4, v);
    } else {                       // zero Yo32 (2112 rows, 16/task): tau 151..282
        int rbase = (tau - 151) * 16;
        for (int j2 = 0; j2 < 16; ++j2)
            ((float4*)(Yo32 + (size_t)(rbase + j2) * 1024))[t] = make_float4(0, 0, 0, 0);
    }
}

// ========== P1: mu (+splits +mun2o), support split-copy, trtri level-1 (grid 200) ==========
__global__ __launch_bounds__(256) void k_p1(const float* sx, const float* mvec,
                                            const float* tl, float* Wbuf) {
    __shared__ __align__(16) float smem[8704];
    WS_DECL
    const int t = threadIdx.x;
    const int lane = t & 63, wv = t >> 6;
    const int tau = blockIdx.x;
    if (tau < 128) {
        float* sX = smem;
        int c = tau >> 2;
        int d = ((tau & 3) << 8) + t;
        int Nj = (int)cons[CO_NJ + c];
        float kap = cons[CO_KAPPA], kN = cons[CO_KN + c];
        float acc = 0.f;
        for (int s = 0; s < Nj; ++s) acc += sx[(size_t)cidx[c * Nk + s] * Dk + d];
        float muv = (kap * mvec[d] + acc) / kN;
        size_t o = (size_t)(2048 + c) * 1024 + d;
        ushort h, m_, l_;
        split1(muv, h, m_, l_);
        sYh[o] = h; sYm[o] = m_; sYl[o] = l_;
        float s2 = wave_red(muv * muv);
        if (lane == 0) sX[wv] = s2;
        __syncthreads();
        if (t == 0) atomicAdd(&mun2o[c], sX[0] + sX[1] + sX[2] + sX[3]);
    } else if (tau < 192) {
        int rbase = (tau - 128) * 16;
        for (int j = 0; j < 16; ++j) {
            int n = rbase + j;
            int srcrow = cidx[(n >> 5) * Nk + (n & 31)];
            float4 v = ((const float4*)(sx + (size_t)srcrow * Dk))[t];
            split_store4(sYh, sYm, sYl, (size_t)(1024 + n) * 1024 + (size_t)t * 4, v);
        }
    } else {
        // trtri level-1: merged T = B*Ainv then -Cinv*T, local 128-block
        float* smA = smem;
        float* smB = smem + 4352;
        const int tx = t & 15, ty = t >> 4;
        const int BIG = 1 << 30;
        int pb = (tau - 192) * 128;
        float acc[4][4] = {};
        mm_task(tl, Dk, pb + 64, BIG, pb, 0, NB,
                W, Dk, pb, BIG, pb, NB, 0, false, 0, 1,
                acc, smA, smB, t, tx, ty);
        {
            float4 ra[4];
            fetch4(ra, W, Dk, pb + 64, BIG, pb + 64, t);
#pragma unroll
            for (int r = 0; r < 4; ++r)
#pragma unroll
                for (int s = 0; s < 4; ++s)
                    smB[(ty * 4 + r) * 68 + tx * 4 + s] = acc[r][s];
            stT(smA, ra, t);
        }
        __syncthreads();
        float acc2[4][4] = {};
        gemm16(smA, smB, acc2, tx, ty);
        __syncthreads();
#pragma unroll
        for (int r = 0; r < 4; ++r)
#pragma unroll
            for (int s = 0; s < 4; ++s)
                W[(size_t)(pb + 64 + ty * 4 + r) * Dk + pb + tx * 4 + s] = -acc2[r][s];
    }
}

// ========== trtri level l phase A: T = B * Ainv ==========
__global__ __launch_bounds__(256) void k_tr_a(const float* tl, float* Wbuf, int h, int ht) {
    __shared__ __align__(16) float smem[8704];
    float* smA = smem;
    float* smB = smem + 4352;
    WS_DECL
    const int t = threadIdx.x;
    const int tx = t & 15, ty = t >> 4;
    const int BIG = 1 << 30;
    int tau = blockIdx.x;
    int p = tau / (ht * ht), rr = tau % (ht * ht);
    int i = rr / ht, j = rr % ht;
    int pb = p * 2 * h;
    float acc[4][4] = {};
    mm_task(tl, Dk, pb + h + i * NB, BIG, pb, 0, NB,
            W, Dk, pb, BIG, pb + j * NB, NB, 0, false, 0, ht,
            acc, smA, smB, t, tx, ty);
    float* Tp = Tb + (size_t)p * h * h;
#pragma unroll
    for (int r = 0; r < 4; ++r)
#pragma unroll
        for (int s = 0; s < 4; ++s)
            Tp[(size_t)(i * NB + ty * 4 + r) * h + j * NB + tx * 4 + s] = acc[r][s];
}

// ========== trtri level l phase B: W_off = -Cinv * T ==========
__global__ __launch_bounds__(256) void k_tr_b(float* Wbuf, int h, int ht) {
    __shared__ __align__(16) float smem[8704];
    float* smA = smem;
    float* smB = smem + 4352;
    WS_DECL
    const int t = threadIdx.x;
    const int tx = t & 15, ty = t >> 4;
    const int BIG = 1 << 30;
    int tau = blockIdx.x;
    int p = tau / (ht * ht), rr = tau % (ht * ht);
    int i = rr / ht, j = rr % ht;
    int pb = p * 2 * h;
    const float* Tp = Tb + (size_t)p * h * h;
    float acc[4][4] = {};
    mm_task(W, Dk, pb + h + i * NB, BIG, pb + h, 0, NB,
            Tp, h, 0, BIG, j * NB, NB, 0, false, 0, ht,
            acc, smA, smB, t, tx, ty);
#pragma unroll
    for (int r = 0; r < 4; ++r)
#pragma unroll
        for (int s = 0; s < 4; ++s)
            W[(size_t)(pb + h + i * NB + ty * 4 + r) * Dk + pb + j * NB + tx * 4 + s] = -acc[r][s];
}

// ========== CVTW: 3-way bf16 split of W, lower-tri masked (grid 256) ==========
__global__ __launch_bounds__(256) void k_cvtw(float* Wbuf) {
    WS_DECL
    const int t = threadIdx.x;
#pragma unroll
    for (int u = 0; u < 4; ++u) {
        unsigned g = blockIdx.x * 1024u + u * 256u + t;   // float4 index
        int row = g >> 8, col4 = (g & 255) * 4;
        float4 v = ((const float4*)W)[g];
        if (col4 + 0 > row) v.x = 0.f;
        if (col4 + 1 > row) v.y = 0.f;
        if (col4 + 2 > row) v.z = 0.f;
        if (col4 + 3 > row) v.w = 0.f;
        split_store4(sWh, sWm, sWl, (size_t)g * 4, v);
    }
}

// ========== YG: Yo32 += Y * W^T, 128x128 tiles, uniform <=8-kstep chunks (grid 340) ==========
__global__ __launch_bounds__(256) void k_yg(float* Wbuf) {
    __shared__ __align__(16) ushort lds[LDS_HW3];
    WS_DECL
    float* Yo32 = Wbuf;
    const int t = threadIdx.x;
    int e = blockIdx.x;
    int q = e / 17, rt = e % 17;
    int jt2, kc;
    if (q < 4)       { jt2 = 7; kc = q; }
    else if (q < 8)  { jt2 = 6; kc = q - 4; }
    else if (q < 11) { jt2 = 5; kc = q - 8; }
    else if (q < 14) { jt2 = 4; kc = q - 11; }
    else if (q < 16) { jt2 = 3; kc = q - 14; }
    else if (q < 18) { jt2 = 2; kc = q - 16; }
    else if (q == 18){ jt2 = 1; kc = 0; }
    else             { jt2 = 0; kc = 0; }
    int ksteps = min(8, 4 * (jt2 + 1) - kc * 8);
    f32x4 acc[4][4] = {};
    tile_gemm3(lds, acc, sYh, sYm, sYl, rt * 128, 2081,
               sWh, sWm, sWl, jt2 * 128, kc * 8, ksteps, t);
    const int w = t >> 6, lr = t & 15, lk = (t >> 4) & 3;
#pragma unroll
    for (int rf = 0; rf < 4; ++rf)
#pragma unroll
        for (int cf = 0; cf < 4; ++cf)
#pragma unroll
            for (int r = 0; r < 4; ++r) {
                int grow = rt * 128 + (w >> 1) * 64 + rf * 16 + lk * 4 + r;
                if (grow < NROWSV)
                    atomicAdd(&Yo32[(size_t)grow * 1024 + jt2 * 128 + (w & 1) * 64 + cf * 16 + lr],
                              acc[rf][cf][r]);
            }
}

// ========== CVTO: Yo32 -> bf16x3 splits; qny from fp32; zero P rows (grid 528) ==========
__global__ __launch_bounds__(256) void k_cvto(float* Wbuf) {
    __shared__ float sred[16];
    WS_DECL
    float* Yo32 = Wbuf;
    const int t = threadIdx.x;
    const int lane = t & 63, wv = t >> 6;
    int rbase = blockIdx.x * 4;
    float4 vv[4];
#pragma unroll
    for (int j = 0; j < 4; ++j) {
        int r = rbase + j;
        float4 v = ((const float4*)(Yo32 + (size_t)r * 1024))[t];
        vv[j] = v;
        split_store4(sOh, sOm, sOl, (size_t)r * 1024 + (size_t)t * 4, v);
    }
    if (rbase < 1024) {
#pragma unroll
        for (int j = 0; j < 4; ++j) {
            float4 v = vv[j];
            float s = v.x * v.x + v.y * v.y + v.z * v.z + v.w * v.w;
            s = wave_red(s);
            if (lane == 0) sred[wv * 4 + j] = s;
        }
        __syncthreads();
        if (t < 4)
            qny[rbase + t] = sred[t] + sred[4 + t] + sred[8 + t] + sred[12 + t];
    }
    if (rbase < 1088) {
#pragma unroll
        for (int j = 0; j < 4; ++j)
            ((float4*)(Yo32 + (size_t)(rbase + j) * 1024))[t] = make_float4(0, 0, 0, 0);
    }
}

// ========== P4M: P += Yo_s*Yo_q^T (288) + QM += mu*qx^T (32), uniform 8 ksteps (grid 320) ==========
__global__ __launch_bounds__(256) void k_p4m(float* Wbuf) {
    __shared__ __align__(16) ushort lds[LDS_HW3];
    WS_DECL
    const int t = threadIdx.x;
    int e = blockIdx.x;
    const int w = t >> 6, lr = t & 15, lk = (t >> 4) & 3;
    f32x4 acc[4][4] = {};
    if (e < 288) {
        int tile = e >> 2, kc = e & 3;    // 72 tiles x 4 k-chunks
        int mt = tile >> 3, qt2 = tile & 7;
        tile_gemm3(lds, acc, sOh, sOm, sOl, 1024 + mt * 128, 2081,
                   sOh, sOm, sOl, qt2 * 128, kc * 8, 8, t);
#pragma unroll
        for (int rf = 0; rf < 4; ++rf)
#pragma unroll
            for (int cf = 0; cf < 4; ++cf)
#pragma unroll
                for (int r = 0; r < 4; ++r) {
                    int n = mt * 128 + (w >> 1) * 64 + rf * 16 + lk * 4 + r;
                    if (n < Nk + Ck + 1)
                        atomicAdd(&P[(size_t)n * 1024 + qt2 * 128 + (w & 1) * 64 + cf * 16 + lr],
                                  acc[rf][cf][r]);
                }
    } else {
        int f = e - 288;
        int qt2 = f >> 2, kc = f & 3;
        tile_gemm3(lds, acc, sYh, sYm, sYl, 2048, 2080,
                   sYh, sYm, sYl, qt2 * 128, kc * 8, 8, t);
#pragma unroll
        for (int rf = 0; rf < 4; ++rf)
#pragma unroll
            for (int cf = 0; cf < 4; ++cf)
#pragma unroll
                for (int r = 0; r < 4; ++r) {
                    int rq = (w >> 1) * 64 + rf * 16 + lk * 4 + r;
                    if (rq < 32)
                        atomicAdd(&QM[(size_t)rq * 1024 + qt2 * 128 + (w & 1) * 64 + cf * 16 + lr],
                                  acc[rf][cf][r]);
                }
    }
}

// ========== GRAM: per-class 34x34 gram (grid 128) ==========
__global__ __launch_bounds__(256) void k_gram(float* Wbuf) {
    __shared__ __align__(16) float smA[34 * 68];
    WS_DECL
    const int t = threadIdx.x;
    const int tau = blockIdx.x;
    int c = tau >> 2, kc = tau & 3;
    float accg[5];
    int iu[5], ju[5];
#pragma unroll
    for (int u = 0; u < 5; ++u) {
        int e = t + u * 256;
        iu[u] = e / 34; ju[u] = e - iu[u] * 34;
        accg[u] = 0.f;
    }
    for (int kt = kc * 4; kt < kc * 4 + 4; ++kt) {
        for (int e2 = t; e2 < 34 * NB; e2 += 256) {
            int i = e2 >> 6, k = e2 & 63;
            int yr = (i < 32) ? (Qk + c * 32 + i) : ((i == 32) ? (Qk + Nk + c) : (Qk + Nk + Ck));
            size_t o = (size_t)yr * 1024 + kt * NB + k;
            smA[i * 68 + k] = bf2f(sOh[o]) + bf2f(sOm[o]) + bf2f(sOl[o]);
        }
        __syncthreads();
#pragma unroll
        for (int u = 0; u < 5; ++u) {
            int e = t + u * 256;
            if (e < 1156) {
                float s = 0.f;
                for (int k = 0; k < NB; ++k) s += smA[iu[u] * 68 + k] * smA[ju[u] * 68 + k];
                accg[u] += s;
            }
        }
        __syncthreads();
    }
#pragma unroll
    for (int u = 0; u < 5; ++u) {
        int e = t + u * 256;
        if (e < 1156)
            atomicAdd(&Mbuf[c * 1224 + iu[u] * 36 + ju[u]], accg[u]);
    }
}

// ========== P5: per-class 34x34 Gauss-Jordan inverse + bias (grid 32, 64 thr) ==========
__global__ __launch_bounds__(64) void k_p5(float* Wbuf) {
    __shared__ __align__(16) float A[34 * 36];   // stride 36 -> 16B-aligned rows
    WS_DECL
    const int t = threadIdx.x;
    const int c = blockIdx.x;
    float kN = cons[CO_KN + c], kap = cons[CO_KAPPA];
    for (int e = t; e < 34 * 34; e += 64) {
        int i = e / 34, j = e - i * 34;
        A[i * 36 + j] = Mbuf[c * 1224 + i * 36 + j];
    }
    __syncthreads();
    if (t == 0) {
        gmm[c] = A[32 * 36 + 32];
        A[32 * 36 + 32] += -1.f / kN;
        A[33 * 36 + 33] += 1.f / kap;
    }
    if (t < 32) A[t * 36 + t] += 1.f;
    __syncthreads();
    float ldacc = 0.f;
    for (int j = 0; j < 34; ++j) {
        float piv = A[j * 36 + j];
        float pinv = 1.f / piv;
        if (t == 0) ldacc += logf(fabsf(piv));
        if (t < 34 && t != j) A[j * 36 + t] *= pinv;   // scale pivot row
        __syncthreads();
        if (t < 34) {
            if (t != j) {
                float f = A[t * 36 + j];
                float4* rowT = (float4*)(A + t * 36);
                const float4* rowJ = (const float4*)(A + j * 36);
#pragma unroll
                for (int k4 = 0; k4 < 8; ++k4) {
                    float4 rv = rowT[k4], pv = rowJ[k4];
                    rv.x -= f * pv.x; rv.y -= f * pv.y;
                    rv.z -= f * pv.z; rv.w -= f * pv.w;
                    rowT[k4] = rv;
                }
                A[t * 36 + 32] -= f * A[j * 36 + 32];
                A[t * 36 + 33] -= f * A[j * 36 + 33];
                A[t * 36 + j] = -f * pinv;            // column j (overwrites racy k=j slot)
            } else {
                A[j * 36 + j] = pinv;
            }
        }
        __syncthreads();
    }
    for (int e = t; e < 34 * 34; e += 64) {
        int i = e / 34, j = e - i * 34;
        Minv[c * 1224 + i * 36 + j] = A[i * 36 + j];
    }
    if (t == 0) {
        float scale = cons[CO_SCALE + c];
        float logdet = (float)Dk * logf(scale) + extraf[0] + logf(kN) + logf(kap) + ldacc;
        cons[CO_BIASF + c] = cons[CO_BIASA + c] - 0.5f * logdet;
    }
}

// ========== P6: epilogue, (qt, c) tasks (grid 512) ==========
__global__ __launch_bounds__(256) void k_p6(float* Wbuf, float* out) {
    __shared__ __align__(16) float smem[3904];
    float* Mi  = smem;          // stride 35 (1190)
    float* wL  = smem + 1200;   // stride 68 (2312)
    float* gsm = smem + 3520;   // 34
    float* red = smem + 3520 + 128;  // 256
    WS_DECL
    const int t = threadIdx.x;
    const int tau = blockIdx.x;
    int qt = tau >> 5, c = tau & 31;
    for (int e = t; e < 34 * 34; e += 256) {
        int i = e / 34, j = e - i * 34;
        Mi[i * 35 + j] = Minv[c * 1224 + i * 36 + j];
    }
    if (t < 34)
        gsm[t] = (t < 32) ? Mbuf[c * 1224 + t * 36 + 32]
                          : ((t == 32) ? gmm[c] : Mbuf[c * 1224 + 33 * 36 + 32]);
    __syncthreads();
    for (int e = t; e < 34 * NB; e += 256) {
        int i = e >> 6, qq = e & 63;
        int prow = (i < 32) ? (c * 32 + i) : ((i == 32) ? (Nk + c) : (Nk + Ck));
        wL[i * 68 + qq] = P[(size_t)prow * Qk + qt * NB + qq] - gsm[i];
    }
    __syncthreads();
    {
        int q = t & 63, part = t >> 6;
        int start = (part < 2) ? part * 9 : 18 + (part - 2) * 8;
        int cnt = (part < 2) ? 9 : 8;
        float partial = 0.f;
        for (int i = start; i < start + cnt; ++i) {
            float v = 0.f;
            for (int j = 0; j < 34; ++j) v += Mi[i * 35 + j] * wL[j * 68 + q];
            partial += v * wL[i * 68 + q];
        }
        red[part * 64 + q] = partial;
    }
    __syncthreads();
    if (t < 64) {
        int q = t;
        float quad = red[q] + red[64 + q] + red[128 + q] + red[192 + q];
        int qg = qt * NB + q;
        float w32 = wL[32 * 68 + q];
        float ydist2 = qny[qg] - 2.f * w32 - gmm[c];
        float dd = qno[qg] + mun2o[c] - 2.f * QM[(size_t)c * Qk + qg];
        float scale = cons[CO_SCALE + c], common = cons[CO_COMMON + c];
        float dist = (1.f - REGP) / scale * (ydist2 - quad) + REGP * dd;
        out[(size_t)qg * Ck + c] = cons[CO_BIASF + c] - cons[CO_COEF + c] * log1pf(dist / common);
    }
}

extern "C" void kernel_launch(void* const* d_in, const int* in_sizes, int n_in,
                              void* d_out, int out_size, void* d_ws, size_t ws_size,
                              hipStream_t stream) {
    const float* sx = (const float*)d_in[0];
    const float* qx = (const float*)d_in[1];
    const int* labels = (const int*)d_in[2];
    const float* mvec = (const float*)d_in[3];
    const float* kappa = (const float*)d_in[4];
    const float* nu = (const float*)d_in[5];
    const float* td = (const float*)d_in[6];
    const float* tl = (const float*)d_in[7];
    float* W = (float*)d_ws;
    float* out = (float*)d_out;

    hipLaunchKernelGGL(k_p0, dim3(283), dim3(256), 0, stream,
                       qx, labels, mvec, kappa, nu, td, tl, W);
    hipLaunchKernelGGL(k_p1, dim3(200), dim3(256), 0, stream, sx, mvec, tl, W);
    for (int l = 2; l <= 4; ++l) {
        int h = 32 << l, ht = h >> 6, pairs = 16 >> l;
        int nt = pairs * ht * ht;
        hipLaunchKernelGGL(k_tr_a, dim3(nt), dim3(256), 0, stream, tl, W, h, ht);
        hipLaunchKernelGGL(k_tr_b, dim3(nt), dim3(256), 0, stream, W, h, ht);
    }
    hipLaunchKernelGGL(k_cvtw, dim3(256), dim3(256), 0, stream, W);
    hipLaunchKernelGGL(k_yg, dim3(340), dim3(256), 0, stream, W);
    hipLaunchKernelGGL(k_cvto, dim3(528), dim3(256), 0, stream, W);
    hipLaunchKernelGGL(k_p4m, dim3(320), dim3(256), 0, stream, W);
    hipLaunchKernelGGL(k_gram, dim3(128), dim3(256), 0, stream, W);
    hipLaunchKernelGGL(k_p5, dim3(32), dim3(64), 0, stream, W);
    hipLaunchKernelGGL(k_p6, dim3(512), dim3(256), 0, stream, W, out);
}